// Round 8
// baseline (205.760 us; speedup 1.0000x reference)
//
#include <hip/hip_runtime.h>

// AttentionGCN forward. B=32, N=1024, F=64, PRE=64, L1=128. Output y[32].
//
// *** MEASUREMENT ROUND: kernels identical to R7; k_prep and k_spmm_mlp are
// *** launched 3x each (idempotent) so dur_us = base + 2*(t_prep + t_spmm).
//
// Pipeline (deterministic, no atomics):
//   k_prep     : disq[b,n] = rsqrt(rowsum(A)); Abf = bf16(A)  (single f32 A pass)
//   k_xt       : xtb[b,f,j] = bf16(disq[b,j] * x[b,j,f])      (transposed B operand)
//   k_spmm_mlp : LDS-staged MFMA spmm -> h in LDS -> values -> logits
//   k_tail     : softmax (redundant per chunk-block) + 128-node pool slice -> vpart
//   k_out      : y[b] = (sum_ch vpart) . Wout + bout

#define N_ 1024
#define F_ 64

typedef short s16x8 __attribute__((ext_vector_type(8)));
typedef float f32x4 __attribute__((ext_vector_type(4)));
typedef unsigned short u16x4 __attribute__((ext_vector_type(4)));
typedef unsigned short u16x8 __attribute__((ext_vector_type(8)));

__device__ __forceinline__ unsigned short bf16rne(float f) {
  union { float f; unsigned u; } v; v.f = f;
  unsigned r = v.u + 0x7fffu + ((v.u >> 16) & 1u);
  return (unsigned short)(r >> 16);
}

__device__ __forceinline__ void fma_row(float (&a)[4], const float4 av,
                                        const float4 x0, const float4 x1,
                                        const float4 x2, const float4 x3) {
  a[0] += av.x * x0.x + av.y * x1.x + av.z * x2.x + av.w * x3.x;
  a[1] += av.x * x0.y + av.y * x1.y + av.z * x2.y + av.w * x3.y;
  a[2] += av.x * x0.z + av.y * x1.z + av.z * x2.z + av.w * x3.z;
  a[3] += av.x * x0.w + av.y * x1.w + av.z * x2.w + av.w * x3.w;
}

// ------- deg + d^-1/2 + A f32->bf16 transcode (one wave per row) -------
__global__ __launch_bounds__(256) void k_prep(const float* __restrict__ A,
                                              float* __restrict__ disq,
                                              unsigned short* __restrict__ Abf) {
  const int row  = blockIdx.x * 4 + (threadIdx.x >> 6);   // [0, B*N)
  const int lane = threadIdx.x & 63;
  const float4* a4 = (const float4*)(A + (size_t)row * N_);
  unsigned short* ob = Abf + (size_t)row * N_;
  float s = 0.f;
#pragma unroll
  for (int it = 0; it < 4; ++it) {
    float4 v = a4[it * 64 + lane];
    s += v.x + v.y + v.z + v.w;
    u16x4 o;
    o[0] = bf16rne(v.x); o[1] = bf16rne(v.y);
    o[2] = bf16rne(v.z); o[3] = bf16rne(v.w);
    *(u16x4*)(ob + (it * 64 + lane) * 4) = o;
  }
#pragma unroll
  for (int off = 32; off > 0; off >>= 1) s += __shfl_down(s, off, 64);
  if (lane == 0) {
    float d = (s != 0.f) ? s : 1.f;
    disq[row] = rsqrtf(d);
  }
}

// ---------------- xtb[b][f][j] = bf16(d_j * x[b][j][f]) ----------------
__global__ __launch_bounds__(256) void k_xt(const float* __restrict__ x,
                                            const float* __restrict__ disq,
                                            unsigned short* __restrict__ xtb) {
  __shared__ float xs[64][68];
  const int b = blockIdx.y, j0 = blockIdx.x * 64, t = threadIdx.x;
  const float* xb = x + ((size_t)b << 16);
  const float* dq = disq + (b << 10);
#pragma unroll
  for (int it = 0; it < 4; ++it) {
    int idx = it * 1024 + t * 4;
    int jj = idx >> 6, ff = idx & 63;
    float4 vv = *(const float4*)&xb[(size_t)(j0 + jj) * F_ + ff];
    float sc = dq[j0 + jj];
    vv.x *= sc; vv.y *= sc; vv.z *= sc; vv.w *= sc;
    *(float4*)&xs[jj][ff] = vv;
  }
  __syncthreads();
  const int f = t & 63, ch = t >> 6;
  u16x8 o0, o1;
#pragma unroll
  for (int jj = 0; jj < 8; ++jj) o0[jj] = bf16rne(xs[ch * 16 + jj][f]);
#pragma unroll
  for (int jj = 0; jj < 8; ++jj) o1[jj] = bf16rne(xs[ch * 16 + 8 + jj][f]);
  unsigned short* dst = xtb + (size_t)(b * 64 + f) * N_ + j0 + ch * 16;
  *(u16x8*)dst = o0;
  *(u16x8*)(dst + 8) = o1;
}

// ------- fused: LDS-staged MFMA spmm -> h (LDS) -> values -> logits -------
__global__ __launch_bounds__(256, 3) void k_spmm_mlp(const unsigned short* __restrict__ Abf,
                                                     const unsigned short* __restrict__ xtb,
                                                     const float* __restrict__ x,
                                                     const float* __restrict__ disq,
                                                     const float* __restrict__ alphap,
                                                     const float* __restrict__ Wpre,
                                                     const float* __restrict__ bpre,
                                                     const float* __restrict__ Wfc1,
                                                     const float* __restrict__ bfc1,
                                                     const float* __restrict__ Wkeys,
                                                     const float* __restrict__ bkeysp,
                                                     float* __restrict__ values,
                                                     float* __restrict__ logits) {
  __shared__ __attribute__((aligned(16))) char smem[54272];
  float (*hs)[68]   = (float(*)[68])(smem);
  float (*wft)[128] = (float(*)[128])(smem + 17408);
  float (*part)[16] = (float(*)[16])(smem + 50176);

  const int t  = threadIdx.x;
  const int b  = blockIdx.x;          // batch
  const int i0 = blockIdx.y * 64;     // row block
  const int w  = t >> 6, l = t & 63;
  const int lr = l & 15, kq = l >> 4;

  const int ar0 = t >> 3;             // 0..31
  const int ac0 = t & 7;
  const int ar1 = ar0 + 32;           // 32..63
  const unsigned short* Asrc0 = Abf + ((size_t)b << 20) + (size_t)(i0 + ar0) * N_ + ac0 * 8;
  const unsigned short* Asrc1 = Abf + ((size_t)b << 20) + (size_t)(i0 + ar1) * N_ + ac0 * 8;
  const unsigned short* Bsrc0 = xtb + (size_t)(b * 64 + ar0) * N_ + ac0 * 8;
  const unsigned short* Bsrc1 = xtb + (size_t)(b * 64 + ar1) * N_ + ac0 * 8;
  const int dst0 = ar0 * 128 + ((ac0 ^ (ar0 & 7)) << 4);
  const int dst1 = ar1 * 128 + ((ac0 ^ (ar0 & 7)) << 4);

  {
    s16x8 ra0 = *(const s16x8*)Asrc0;
    s16x8 ra1 = *(const s16x8*)Asrc1;
    s16x8 rb0 = *(const s16x8*)Bsrc0;
    s16x8 rb1 = *(const s16x8*)Bsrc1;
    *(s16x8*)(smem + dst0) = ra0;
    *(s16x8*)(smem + dst1) = ra1;
    *(s16x8*)(smem + 8192 + dst0) = rb0;
    *(s16x8*)(smem + 8192 + dst1) = rb1;
  }
  __syncthreads();

  f32x4 acc0 = {0.f, 0.f, 0.f, 0.f}, acc1 = acc0, acc2 = acc0, acc3 = acc0;
  const int arow = w * 16 + lr;
  const int sw = (lr & 7) << 4;
  int cur = 0;

  for (int ks = 0; ks < 16; ++ks) {
    s16x8 na0, na1, nb0, nb1;
    if (ks < 15) {
      const int ko = (ks + 1) * 64;
      na0 = *(const s16x8*)(Asrc0 + ko);
      na1 = *(const s16x8*)(Asrc1 + ko);
      nb0 = *(const s16x8*)(Bsrc0 + ko);
      nb1 = *(const s16x8*)(Bsrc1 + ko);
    }
    const char* cb = smem + cur * 16384;
#pragma unroll
    for (int s = 0; s < 2; ++s) {
      const int ch = ((kq + 4 * s) << 4);
      s16x8 af = *(const s16x8*)(cb + arow * 128 + (ch ^ sw));
      s16x8 b0 = *(const s16x8*)(cb + 8192 + (0 * 16 + lr) * 128 + (ch ^ sw));
      s16x8 b1 = *(const s16x8*)(cb + 8192 + (1 * 16 + lr) * 128 + (ch ^ sw));
      s16x8 b2 = *(const s16x8*)(cb + 8192 + (2 * 16 + lr) * 128 + (ch ^ sw));
      s16x8 b3 = *(const s16x8*)(cb + 8192 + (3 * 16 + lr) * 128 + (ch ^ sw));
      acc0 = __builtin_amdgcn_mfma_f32_16x16x32_bf16(af, b0, acc0, 0, 0, 0);
      acc1 = __builtin_amdgcn_mfma_f32_16x16x32_bf16(af, b1, acc1, 0, 0, 0);
      acc2 = __builtin_amdgcn_mfma_f32_16x16x32_bf16(af, b2, acc2, 0, 0, 0);
      acc3 = __builtin_amdgcn_mfma_f32_16x16x32_bf16(af, b3, acc3, 0, 0, 0);
    }
    if (ks < 15) {
      char* nbuf = smem + (cur ^ 1) * 16384;
      *(s16x8*)(nbuf + dst0) = na0;
      *(s16x8*)(nbuf + dst1) = na1;
      *(s16x8*)(nbuf + 8192 + dst0) = nb0;
      *(s16x8*)(nbuf + 8192 + dst1) = nb1;
    }
    __syncthreads();
    cur ^= 1;
  }

  const float alpha = alphap[0];
  const float* dq = disq + (b << 10);
  const float* xb = x + ((size_t)b << 16);
  const int rl = w * 16 + kq * 4;
#pragma unroll
  for (int r = 0; r < 4; ++r) {
    float di = dq[i0 + rl + r];
    size_t ro = (size_t)(i0 + rl + r) * F_;
    hs[rl + r][0  + lr] = alpha * xb[ro + 0  + lr] + di * acc0[r];
    hs[rl + r][16 + lr] = alpha * xb[ro + 16 + lr] + di * acc1[r];
    hs[rl + r][32 + lr] = alpha * xb[ro + 32 + lr] + di * acc2[r];
    hs[rl + r][48 + lr] = alpha * xb[ro + 48 + lr] + di * acc3[r];
  }
#pragma unroll
  for (int it = 0; it < 4; ++it) {
    int idx = it * 1024 + t * 4;
    float4 wv = *(const float4*)&Wpre[idx];
    int p = idx >> 6, f = idx & 63;
    wft[f + 0][p] = wv.x; wft[f + 1][p] = wv.y; wft[f + 2][p] = wv.z; wft[f + 3][p] = wv.w;
  }
  __syncthreads();

  const size_t base = ((size_t)(b * 16 + blockIdx.y)) * 4096;
  const int cg = t & 15, rg = t >> 4;
  float acc[4][4] = {{0.f}};
#pragma unroll
  for (int q = 0; q < 16; ++q) {
    float4 xv0 = *(float4*)&wft[q * 4 + 0][cg * 4];
    float4 xv1 = *(float4*)&wft[q * 4 + 1][cg * 4];
    float4 xv2 = *(float4*)&wft[q * 4 + 2][cg * 4];
    float4 xv3 = *(float4*)&wft[q * 4 + 3][cg * 4];
#pragma unroll
    for (int k = 0; k < 4; ++k) {
      float4 av = *(float4*)&hs[rg * 4 + k][q * 4];
      fma_row(acc[k], av, xv0, xv1, xv2, xv3);
    }
  }
  float4 bp = *(const float4*)&bpre[cg * 4];
  __syncthreads();
#pragma unroll
  for (int k = 0; k < 4; ++k) {
    float4 o;
    o.x = fmaxf(acc[k][0] + bp.x, 0.f);
    o.y = fmaxf(acc[k][1] + bp.y, 0.f);
    o.z = fmaxf(acc[k][2] + bp.z, 0.f);
    o.w = fmaxf(acc[k][3] + bp.w, 0.f);
    *(float4*)&hs[rg * 4 + k][cg * 4] = o;
    *(float4*)&values[base + (size_t)(rg * 4 + k) * 64 + cg * 4] = o;
  }
#pragma unroll
  for (int it = 0; it < 8; ++it) {
    int idx = it * 1024 + t * 4;
    int ll = idx >> 6, p = idx & 63;
    float4 wv = *(const float4*)&Wfc1[idx];
    wft[p + 0][ll] = wv.x; wft[p + 1][ll] = wv.y; wft[p + 2][ll] = wv.z; wft[p + 3][ll] = wv.w;
  }
  __syncthreads();

  const int lg = cg;
  float acc_a[4][4] = {{0.f}};
  float acc_b[4][4] = {{0.f}};
#pragma unroll
  for (int q = 0; q < 16; ++q) {
    float4 w0a = *(float4*)&wft[q * 4 + 0][lg * 8];
    float4 w0b = *(float4*)&wft[q * 4 + 0][lg * 8 + 4];
    float4 w1a = *(float4*)&wft[q * 4 + 1][lg * 8];
    float4 w1b = *(float4*)&wft[q * 4 + 1][lg * 8 + 4];
    float4 w2a = *(float4*)&wft[q * 4 + 2][lg * 8];
    float4 w2b = *(float4*)&wft[q * 4 + 2][lg * 8 + 4];
    float4 w3a = *(float4*)&wft[q * 4 + 3][lg * 8];
    float4 w3b = *(float4*)&wft[q * 4 + 3][lg * 8 + 4];
#pragma unroll
    for (int k = 0; k < 4; ++k) {
      float4 vv = *(float4*)&hs[rg * 4 + k][q * 4];
      fma_row(acc_a[k], vv, w0a, w1a, w2a, w3a);
      fma_row(acc_b[k], vv, w0b, w1b, w2b, w3b);
    }
  }
  float4 bfa = *(const float4*)&bfc1[lg * 8];
  float4 bfb = *(const float4*)&bfc1[lg * 8 + 4];
  float4 wka = *(const float4*)&Wkeys[lg * 8];
  float4 wkb = *(const float4*)&Wkeys[lg * 8 + 4];
#pragma unroll
  for (int k = 0; k < 4; ++k) {
    float lp = 0.f;
    lp += fmaxf(acc_a[k][0] + bfa.x, 0.f) * wka.x;
    lp += fmaxf(acc_a[k][1] + bfa.y, 0.f) * wka.y;
    lp += fmaxf(acc_a[k][2] + bfa.z, 0.f) * wka.z;
    lp += fmaxf(acc_a[k][3] + bfa.w, 0.f) * wka.w;
    lp += fmaxf(acc_b[k][0] + bfb.x, 0.f) * wkb.x;
    lp += fmaxf(acc_b[k][1] + bfb.y, 0.f) * wkb.y;
    lp += fmaxf(acc_b[k][2] + bfb.z, 0.f) * wkb.z;
    lp += fmaxf(acc_b[k][3] + bfb.w, 0.f) * wkb.w;
    part[rg * 4 + k][lg] = lp;
  }
  __syncthreads();
  if (t < 64) {
    float s = bkeysp[0];
#pragma unroll
    for (int g = 0; g < 16; ++g) s += part[t][g];
    logits[(b * 16 + blockIdx.y) * 64 + t] = s;
  }
}

// ------- tail: redundant softmax per chunk-block + 128-node pool slice -------
__global__ __launch_bounds__(1024) void k_tail(const float* __restrict__ logits,
                                               const float* __restrict__ values,
                                               float* __restrict__ vpart) {
  const int c = blockIdx.x, b = blockIdx.y, t = threadIdx.x;
  __shared__ float sc[1024];
  __shared__ float red[16];
  __shared__ float pool[16][64];
  const float isq2 = 0.70710678118654752f;
  float lv = logits[(b << 10) + t] * isq2;
  float m = lv;
#pragma unroll
  for (int off = 32; off > 0; off >>= 1) m = fmaxf(m, __shfl_xor(m, off, 64));
  if ((t & 63) == 0) red[t >> 6] = m;
  __syncthreads();
  m = red[0];
#pragma unroll
  for (int i = 1; i < 16; ++i) m = fmaxf(m, red[i]);
  float e = expf(lv - m);
  float s = e;
#pragma unroll
  for (int off = 32; off > 0; off >>= 1) s += __shfl_xor(s, off, 64);
  __syncthreads();
  if ((t & 63) == 0) red[t >> 6] = s;
  __syncthreads();
  s = red[0];
#pragma unroll
  for (int i = 1; i < 16; ++i) s += red[i];
  sc[t] = e * (1.f / s);
  __syncthreads();
  const int col = t & 63, g = t >> 6;
  const float* vb = values + ((size_t)b << 16);
  float acc = 0.f;
#pragma unroll
  for (int k = 0; k < 8; ++k) {
    int n = c * 128 + g + 16 * k;
    acc += sc[n] * vb[(size_t)n * 64 + col];
  }
  pool[g][col] = acc;
  __syncthreads();
  if (t < 64) {
    float v = 0.f;
#pragma unroll
    for (int gg = 0; gg < 16; ++gg) v += pool[gg][t];
    vpart[(b * 8 + c) * 64 + t] = v;
  }
}

// ---------------- final y ----------------
__global__ __launch_bounds__(256) void k_out(const float* __restrict__ vpart,
                                             const float* __restrict__ Wout,
                                             const float* __restrict__ boutp,
                                             float* __restrict__ y) {
  const int t = threadIdx.x, w = t >> 6, lane = t & 63;
#pragma unroll
  for (int it = 0; it < 8; ++it) {
    int b = w * 8 + it;
    float v = 0.f;
#pragma unroll
    for (int ch = 0; ch < 8; ++ch) v += vpart[(b * 8 + ch) * 64 + lane];
    float p = v * Wout[lane];
#pragma unroll
    for (int off = 32; off > 0; off >>= 1) p += __shfl_down(p, off, 64);
    if (lane == 0) y[b] = p + boutp[0];
  }
}

extern "C" void kernel_launch(void* const* d_in, const int* in_sizes, int n_in,
                              void* d_out, int out_size, void* d_ws, size_t ws_size,
                              hipStream_t stream) {
  const float* x     = (const float*)d_in[0];
  const float* A     = (const float*)d_in[1];
  const float* alpha = (const float*)d_in[2];
  const float* Wpre  = (const float*)d_in[3];
  const float* bpre  = (const float*)d_in[4];
  const float* Wfc1  = (const float*)d_in[5];
  const float* bfc1  = (const float*)d_in[6];
  const float* Wkeys = (const float*)d_in[7];
  const float* bkeys = (const float*)d_in[8];
  const float* Wout  = (const float*)d_in[9];
  const float* bout  = (const float*)d_in[10];
  float* y = (float*)d_out;

  float* ws     = (float*)d_ws;
  float* disq   = ws;                   // 32768 f32
  float* values = disq + 32768;         // 2097152 f32
  float* logits = values + 2097152;     // 32768 f32
  float* vpart  = logits + 32768;       // 16384 f32
  unsigned short* xtb = (unsigned short*)(vpart + 16384);   // 2097152 bf16
  unsigned short* Abf = xtb + 2097152;                      // 33554432 bf16 (64 MB)

  // MEASUREMENT: k_prep x3 and k_spmm_mlp x3 (idempotent).
  // dur_us = base + 2*t_prep + 2*t_spmm.
  k_prep    <<<dim3(8192),   dim3(256),  0, stream>>>(A, disq, Abf);
  k_prep    <<<dim3(8192),   dim3(256),  0, stream>>>(A, disq, Abf);
  k_prep    <<<dim3(8192),   dim3(256),  0, stream>>>(A, disq, Abf);
  k_xt      <<<dim3(16, 32), dim3(256),  0, stream>>>(x, disq, xtb);
  k_spmm_mlp<<<dim3(32, 16), dim3(256),  0, stream>>>(Abf, xtb, x, disq, alpha,
                                                      Wpre, bpre, Wfc1, bfc1, Wkeys, bkeys,
                                                      values, logits);
  k_spmm_mlp<<<dim3(32, 16), dim3(256),  0, stream>>>(Abf, xtb, x, disq, alpha,
                                                      Wpre, bpre, Wfc1, bfc1, Wkeys, bkeys,
                                                      values, logits);
  k_spmm_mlp<<<dim3(32, 16), dim3(256),  0, stream>>>(Abf, xtb, x, disq, alpha,
                                                      Wpre, bpre, Wfc1, bfc1, Wkeys, bkeys,
                                                      values, logits);
  k_tail    <<<dim3(8, 32),  dim3(1024), 0, stream>>>(logits, values, vpart);
  k_out     <<<dim3(1),      dim3(256),  0, stream>>>(vpart, Wout, bout, y);
}

// Round 9
// 78.061 us; speedup vs baseline: 2.6359x; 2.6359x over previous
//
#include <hip/hip_runtime.h>

// AttentionGCN forward. B=32, N=1024, F=64, PRE=64, L1=128. Output y[32].
//
// Pipeline (5 kernels, deterministic, no atomics):
//   k_prep     : disq[b,n] = rsqrt(rowsum(A)); Abf = bf16(A)  (single f32 A pass)
//   k_xt       : xtb[b,f,j] = bf16(disq[b,j] * x[b,j,f])      (transposed B operand)
//   k_spmm_mlp : MFMA spmm staged via global_load_lds DMA (pre-swizzled source,
//                linear LDS dest, XOR-swizzled reads) -> h in LDS -> values -> logits
//   k_tail     : softmax (redundant per chunk-block) + 128-node pool slice -> vpart
//   k_out      : y[b] = (sum_ch vpart) . Wout + bout

#define N_ 1024
#define F_ 64

typedef short s16x8 __attribute__((ext_vector_type(8)));
typedef float f32x4 __attribute__((ext_vector_type(4)));
typedef unsigned short u16x4 __attribute__((ext_vector_type(4)));
typedef unsigned short u16x8 __attribute__((ext_vector_type(8)));

__device__ __forceinline__ unsigned short bf16rne(float f) {
  union { float f; unsigned u; } v; v.f = f;
  unsigned r = v.u + 0x7fffu + ((v.u >> 16) & 1u);
  return (unsigned short)(r >> 16);
}

__device__ __forceinline__ void fma_row(float (&a)[4], const float4 av,
                                        const float4 x0, const float4 x1,
                                        const float4 x2, const float4 x3) {
  a[0] += av.x * x0.x + av.y * x1.x + av.z * x2.x + av.w * x3.x;
  a[1] += av.x * x0.y + av.y * x1.y + av.z * x2.y + av.w * x3.y;
  a[2] += av.x * x0.z + av.y * x1.z + av.z * x2.z + av.w * x3.z;
  a[3] += av.x * x0.w + av.y * x1.w + av.z * x2.w + av.w * x3.w;
}

// global -> LDS direct DMA, 16B per lane; LDS dest = wave-uniform base + lane*16
__device__ __forceinline__ void stage16(const unsigned short* g, void* l) {
  auto gp = reinterpret_cast<const __attribute__((address_space(1))) void*>(
      reinterpret_cast<uintptr_t>(g));
  auto lp = reinterpret_cast<__attribute__((address_space(3))) void*>(
      reinterpret_cast<uintptr_t>(l));
  __builtin_amdgcn_global_load_lds(gp, lp, 16, 0, 0);
}

// ------- deg + d^-1/2 + A f32->bf16 transcode (one wave per row) -------
__global__ __launch_bounds__(256) void k_prep(const float* __restrict__ A,
                                              float* __restrict__ disq,
                                              unsigned short* __restrict__ Abf) {
  const int row  = blockIdx.x * 4 + (threadIdx.x >> 6);   // [0, B*N)
  const int lane = threadIdx.x & 63;
  const float4* a4 = (const float4*)(A + (size_t)row * N_);
  unsigned short* ob = Abf + (size_t)row * N_;
  float s = 0.f;
#pragma unroll
  for (int it = 0; it < 4; ++it) {
    float4 v = a4[it * 64 + lane];
    s += v.x + v.y + v.z + v.w;
    u16x4 o;
    o[0] = bf16rne(v.x); o[1] = bf16rne(v.y);
    o[2] = bf16rne(v.z); o[3] = bf16rne(v.w);
    *(u16x4*)(ob + (it * 64 + lane) * 4) = o;
  }
#pragma unroll
  for (int off = 32; off > 0; off >>= 1) s += __shfl_down(s, off, 64);
  if (lane == 0) {
    float d = (s != 0.f) ? s : 1.f;
    disq[row] = rsqrtf(d);
  }
}

// ---------------- xtb[b][f][j] = bf16(d_j * x[b][j][f]) ----------------
__global__ __launch_bounds__(256) void k_xt(const float* __restrict__ x,
                                            const float* __restrict__ disq,
                                            unsigned short* __restrict__ xtb) {
  __shared__ float xs[64][68];
  const int b = blockIdx.y, j0 = blockIdx.x * 64, t = threadIdx.x;
  const float* xb = x + ((size_t)b << 16);
  const float* dq = disq + (b << 10);
#pragma unroll
  for (int it = 0; it < 4; ++it) {
    int idx = it * 1024 + t * 4;
    int jj = idx >> 6, ff = idx & 63;
    float4 vv = *(const float4*)&xb[(size_t)(j0 + jj) * F_ + ff];
    float sc = dq[j0 + jj];
    vv.x *= sc; vv.y *= sc; vv.z *= sc; vv.w *= sc;
    *(float4*)&xs[jj][ff] = vv;
  }
  __syncthreads();
  const int f = t & 63, ch = t >> 6;
  u16x8 o0, o1;
#pragma unroll
  for (int jj = 0; jj < 8; ++jj) o0[jj] = bf16rne(xs[ch * 16 + jj][f]);
#pragma unroll
  for (int jj = 0; jj < 8; ++jj) o1[jj] = bf16rne(xs[ch * 16 + 8 + jj][f]);
  unsigned short* dst = xtb + (size_t)(b * 64 + f) * N_ + j0 + ch * 16;
  *(u16x8*)dst = o0;
  *(u16x8*)(dst + 8) = o1;
}

// ------- fused: DMA-staged MFMA spmm -> h (LDS) -> values -> logits -------
// Grid (32 batches, 16 row-blocks). 4 waves; wave w owns output rows w*16..+15.
// Staging roles: wave 0/1 -> A rows 0-31/32-63; wave 2/3 -> B rows 0-31/32-63.
// LDS content: region[r*128 + q*16] = global[r][chunk q ^ (r&7)] (pre-swizzled
// global source, linear LDS dest); fragment reads XOR with (row&7)<<4.
__global__ __launch_bounds__(256, 3) void k_spmm_mlp(const unsigned short* __restrict__ Abf,
                                                     const unsigned short* __restrict__ xtb,
                                                     const float* __restrict__ x,
                                                     const float* __restrict__ disq,
                                                     const float* __restrict__ alphap,
                                                     const float* __restrict__ Wpre,
                                                     const float* __restrict__ bpre,
                                                     const float* __restrict__ Wfc1,
                                                     const float* __restrict__ bfc1,
                                                     const float* __restrict__ Wkeys,
                                                     const float* __restrict__ bkeysp,
                                                     float* __restrict__ values,
                                                     float* __restrict__ logits) {
  // LDS union: [0,16384) buf0 (A 8K | B 8K), [16384,32768) buf1.
  // MLP aliases: hs f32[64][68] @0, wft f32[64][128] @17408, part f32[64][16] @50176.
  __shared__ __attribute__((aligned(16))) char smem[54272];
  float (*hs)[68]   = (float(*)[68])(smem);
  float (*wft)[128] = (float(*)[128])(smem + 17408);
  float (*part)[16] = (float(*)[16])(smem + 50176);

  const int t  = threadIdx.x;
  const int b  = blockIdx.x;          // batch
  const int i0 = blockIdx.y * 64;     // row block
  const int w  = t >> 6, l = t & 63;
  const int lr = l & 15, kq = l >> 4;

  // ---- DMA staging addressing ----
  const int srow = l >> 3;                       // 0..7 within 8-row group
  const int sch  = ((l & 7) ^ srow) * 8;         // pre-swizzled source chunk (shorts)
  const int half = (w & 1) * 32;                 // row half this wave stages
  const unsigned short* gsA = Abf + ((size_t)b << 20) + (size_t)(i0 + half + srow) * N_ + sch;
  const unsigned short* gsB = xtb + (size_t)(b * 64 + half + srow) * N_ + sch;
  const int loff = half * 128;                   // LDS byte offset of this half

  auto STAGE = [&](char* bufp, int ksv) {
    const int ko = ksv * 64;
    if (w < 2) {
#pragma unroll
      for (int j = 0; j < 4; ++j)
        stage16(gsA + (size_t)j * 8 * N_ + ko, bufp + loff + j * 1024);
    } else {
#pragma unroll
      for (int j = 0; j < 4; ++j)
        stage16(gsB + (size_t)j * 8 * N_ + ko, bufp + 8192 + loff + j * 1024);
    }
  };

  // ---- prologue: DMA K-step 0 into buf0 ----
  STAGE(smem, 0);
  __syncthreads();   // implicit vmcnt(0): DMA complete

  f32x4 acc0 = {0.f, 0.f, 0.f, 0.f}, acc1 = acc0, acc2 = acc0, acc3 = acc0;
  const int arow = w * 16 + lr;
  const int sw = (lr & 7) << 4;       // row-XOR for fragment reads
  int cur = 0;

  for (int ks = 0; ks < 16; ++ks) {
    if (ks < 15) STAGE(smem + (cur ^ 1) * 16384, ks + 1);  // fire-and-forget DMA
    const char* cb = smem + cur * 16384;
#pragma unroll
    for (int s = 0; s < 2; ++s) {
      const int ch = ((kq + 4 * s) << 4);   // chunk byte within row
      s16x8 af = *(const s16x8*)(cb + arow * 128 + (ch ^ sw));
      s16x8 b0 = *(const s16x8*)(cb + 8192 + (0 * 16 + lr) * 128 + (ch ^ sw));
      s16x8 b1 = *(const s16x8*)(cb + 8192 + (1 * 16 + lr) * 128 + (ch ^ sw));
      s16x8 b2 = *(const s16x8*)(cb + 8192 + (2 * 16 + lr) * 128 + (ch ^ sw));
      s16x8 b3 = *(const s16x8*)(cb + 8192 + (3 * 16 + lr) * 128 + (ch ^ sw));
      acc0 = __builtin_amdgcn_mfma_f32_16x16x32_bf16(af, b0, acc0, 0, 0, 0);
      acc1 = __builtin_amdgcn_mfma_f32_16x16x32_bf16(af, b1, acc1, 0, 0, 0);
      acc2 = __builtin_amdgcn_mfma_f32_16x16x32_bf16(af, b2, acc2, 0, 0, 0);
      acc3 = __builtin_amdgcn_mfma_f32_16x16x32_bf16(af, b3, acc3, 0, 0, 0);
    }
    __syncthreads();   // drains DMA (vmcnt) after full MFMA phase of cover
    cur ^= 1;
  }

  // ---- epilogue: h tile into LDS (staging bufs now dead) ----
  const float alpha = alphap[0];
  const float* dq = disq + (b << 10);
  const float* xb = x + ((size_t)b << 16);
  const int rl = w * 16 + kq * 4;     // local row base for C/D (col=lr, row=kq*4+r)
#pragma unroll
  for (int r = 0; r < 4; ++r) {
    float di = dq[i0 + rl + r];
    size_t ro = (size_t)(i0 + rl + r) * F_;
    hs[rl + r][0  + lr] = alpha * xb[ro + 0  + lr] + di * acc0[r];
    hs[rl + r][16 + lr] = alpha * xb[ro + 16 + lr] + di * acc1[r];
    hs[rl + r][32 + lr] = alpha * xb[ro + 32 + lr] + di * acc2[r];
    hs[rl + r][48 + lr] = alpha * xb[ro + 48 + lr] + di * acc3[r];
  }
  // load Wpre transposed into wft while hs writes settle
#pragma unroll
  for (int it = 0; it < 4; ++it) {
    int idx = it * 1024 + t * 4;
    float4 wv = *(const float4*)&Wpre[idx];
    int p = idx >> 6, f = idx & 63;
    wft[f + 0][p] = wv.x; wft[f + 1][p] = wv.y; wft[f + 2][p] = wv.z; wft[f + 3][p] = wv.w;
  }
  __syncthreads();

  // ---- phase 1: values tile ----
  const size_t base = ((size_t)(b * 16 + blockIdx.y)) * 4096;
  const int cg = t & 15, rg = t >> 4;
  float acc[4][4] = {{0.f}};
#pragma unroll
  for (int q = 0; q < 16; ++q) {
    float4 xv0 = *(float4*)&wft[q * 4 + 0][cg * 4];
    float4 xv1 = *(float4*)&wft[q * 4 + 1][cg * 4];
    float4 xv2 = *(float4*)&wft[q * 4 + 2][cg * 4];
    float4 xv3 = *(float4*)&wft[q * 4 + 3][cg * 4];
#pragma unroll
    for (int k = 0; k < 4; ++k) {
      float4 av = *(float4*)&hs[rg * 4 + k][q * 4];
      fma_row(acc[k], av, xv0, xv1, xv2, xv3);
    }
  }
  float4 bp = *(const float4*)&bpre[cg * 4];
  __syncthreads();   // phase-1 reads of hs/wft complete before overwrite
#pragma unroll
  for (int k = 0; k < 4; ++k) {
    float4 o;
    o.x = fmaxf(acc[k][0] + bp.x, 0.f);
    o.y = fmaxf(acc[k][1] + bp.y, 0.f);
    o.z = fmaxf(acc[k][2] + bp.z, 0.f);
    o.w = fmaxf(acc[k][3] + bp.w, 0.f);
    *(float4*)&hs[rg * 4 + k][cg * 4] = o;
    *(float4*)&values[base + (size_t)(rg * 4 + k) * 64 + cg * 4] = o;
  }
#pragma unroll
  for (int it = 0; it < 8; ++it) {
    int idx = it * 1024 + t * 4;
    int ll = idx >> 6, p = idx & 63;
    float4 wv = *(const float4*)&Wfc1[idx];
    wft[p + 0][ll] = wv.x; wft[p + 1][ll] = wv.y; wft[p + 2][ll] = wv.z; wft[p + 3][ll] = wv.w;
  }
  __syncthreads();

  // ---- phase 2: logits ----
  const int lg = cg;
  float acc_a[4][4] = {{0.f}};
  float acc_b[4][4] = {{0.f}};
#pragma unroll
  for (int q = 0; q < 16; ++q) {
    float4 w0a = *(float4*)&wft[q * 4 + 0][lg * 8];
    float4 w0b = *(float4*)&wft[q * 4 + 0][lg * 8 + 4];
    float4 w1a = *(float4*)&wft[q * 4 + 1][lg * 8];
    float4 w1b = *(float4*)&wft[q * 4 + 1][lg * 8 + 4];
    float4 w2a = *(float4*)&wft[q * 4 + 2][lg * 8];
    float4 w2b = *(float4*)&wft[q * 4 + 2][lg * 8 + 4];
    float4 w3a = *(float4*)&wft[q * 4 + 3][lg * 8];
    float4 w3b = *(float4*)&wft[q * 4 + 3][lg * 8 + 4];
#pragma unroll
    for (int k = 0; k < 4; ++k) {
      float4 vv = *(float4*)&hs[rg * 4 + k][q * 4];
      fma_row(acc_a[k], vv, w0a, w1a, w2a, w3a);
      fma_row(acc_b[k], vv, w0b, w1b, w2b, w3b);
    }
  }
  float4 bfa = *(const float4*)&bfc1[lg * 8];
  float4 bfb = *(const float4*)&bfc1[lg * 8 + 4];
  float4 wka = *(const float4*)&Wkeys[lg * 8];
  float4 wkb = *(const float4*)&Wkeys[lg * 8 + 4];
#pragma unroll
  for (int k = 0; k < 4; ++k) {
    float lp = 0.f;
    lp += fmaxf(acc_a[k][0] + bfa.x, 0.f) * wka.x;
    lp += fmaxf(acc_a[k][1] + bfa.y, 0.f) * wka.y;
    lp += fmaxf(acc_a[k][2] + bfa.z, 0.f) * wka.z;
    lp += fmaxf(acc_a[k][3] + bfa.w, 0.f) * wka.w;
    lp += fmaxf(acc_b[k][0] + bfb.x, 0.f) * wkb.x;
    lp += fmaxf(acc_b[k][1] + bfb.y, 0.f) * wkb.y;
    lp += fmaxf(acc_b[k][2] + bfb.z, 0.f) * wkb.z;
    lp += fmaxf(acc_b[k][3] + bfb.w, 0.f) * wkb.w;
    part[rg * 4 + k][lg] = lp;
  }
  __syncthreads();
  if (t < 64) {
    float s = bkeysp[0];
#pragma unroll
    for (int g = 0; g < 16; ++g) s += part[t][g];
    logits[(b * 16 + blockIdx.y) * 64 + t] = s;
  }
}

// ------- tail: redundant softmax per chunk-block + 128-node pool slice -------
__global__ __launch_bounds__(1024) void k_tail(const float* __restrict__ logits,
                                               const float* __restrict__ values,
                                               float* __restrict__ vpart) {
  const int c = blockIdx.x, b = blockIdx.y, t = threadIdx.x;
  __shared__ float sc[1024];
  __shared__ float red[16];
  __shared__ float pool[16][64];
  const float isq2 = 0.70710678118654752f;
  float lv = logits[(b << 10) + t] * isq2;
  float m = lv;
#pragma unroll
  for (int off = 32; off > 0; off >>= 1) m = fmaxf(m, __shfl_xor(m, off, 64));
  if ((t & 63) == 0) red[t >> 6] = m;
  __syncthreads();
  m = red[0];
#pragma unroll
  for (int i = 1; i < 16; ++i) m = fmaxf(m, red[i]);
  float e = expf(lv - m);
  float s = e;
#pragma unroll
  for (int off = 32; off > 0; off >>= 1) s += __shfl_xor(s, off, 64);
  __syncthreads();
  if ((t & 63) == 0) red[t >> 6] = s;
  __syncthreads();
  s = red[0];
#pragma unroll
  for (int i = 1; i < 16; ++i) s += red[i];
  sc[t] = e * (1.f / s);
  __syncthreads();
  const int col = t & 63, g = t >> 6;
  const float* vb = values + ((size_t)b << 16);
  float acc = 0.f;
#pragma unroll
  for (int k = 0; k < 8; ++k) {
    int n = c * 128 + g + 16 * k;
    acc += sc[n] * vb[(size_t)n * 64 + col];
  }
  pool[g][col] = acc;
  __syncthreads();
  if (t < 64) {
    float v = 0.f;
#pragma unroll
    for (int gg = 0; gg < 16; ++gg) v += pool[gg][t];
    vpart[(b * 8 + c) * 64 + t] = v;
  }
}

// ---------------- final y ----------------
__global__ __launch_bounds__(256) void k_out(const float* __restrict__ vpart,
                                             const float* __restrict__ Wout,
                                             const float* __restrict__ boutp,
                                             float* __restrict__ y) {
  const int t = threadIdx.x, w = t >> 6, lane = t & 63;
#pragma unroll
  for (int it = 0; it < 8; ++it) {
    int b = w * 8 + it;
    float v = 0.f;
#pragma unroll
    for (int ch = 0; ch < 8; ++ch) v += vpart[(b * 8 + ch) * 64 + lane];
    float p = v * Wout[lane];
#pragma unroll
    for (int off = 32; off > 0; off >>= 1) p += __shfl_down(p, off, 64);
    if (lane == 0) y[b] = p + boutp[0];
  }
}

extern "C" void kernel_launch(void* const* d_in, const int* in_sizes, int n_in,
                              void* d_out, int out_size, void* d_ws, size_t ws_size,
                              hipStream_t stream) {
  const float* x     = (const float*)d_in[0];
  const float* A     = (const float*)d_in[1];
  const float* alpha = (const float*)d_in[2];
  const float* Wpre  = (const float*)d_in[3];
  const float* bpre  = (const float*)d_in[4];
  const float* Wfc1  = (const float*)d_in[5];
  const float* bfc1  = (const float*)d_in[6];
  const float* Wkeys = (const float*)d_in[7];
  const float* bkeys = (const float*)d_in[8];
  const float* Wout  = (const float*)d_in[9];
  const float* bout  = (const float*)d_in[10];
  float* y = (float*)d_out;

  float* ws     = (float*)d_ws;
  float* disq   = ws;                   // 32768 f32
  float* values = disq + 32768;         // 2097152 f32
  float* logits = values + 2097152;     // 32768 f32
  float* vpart  = logits + 32768;       // 16384 f32
  unsigned short* xtb = (unsigned short*)(vpart + 16384);   // 2097152 bf16
  unsigned short* Abf = xtb + 2097152;                      // 33554432 bf16 (64 MB)

  k_prep    <<<dim3(8192),   dim3(256),  0, stream>>>(A, disq, Abf);
  k_xt      <<<dim3(16, 32), dim3(256),  0, stream>>>(x, disq, xtb);
  k_spmm_mlp<<<dim3(32, 16), dim3(256),  0, stream>>>(Abf, xtb, x, disq, alpha,
                                                      Wpre, bpre, Wfc1, bfc1, Wkeys, bkeys,
                                                      values, logits);
  k_tail    <<<dim3(8, 32),  dim3(1024), 0, stream>>>(logits, values, vpart);
  k_out     <<<dim3(1),      dim3(256),  0, stream>>>(vpart, Wout, bout, y);
}

// Round 10
// 77.038 us; speedup vs baseline: 2.6709x; 1.0133x over previous
//
#include <hip/hip_runtime.h>

// AttentionGCN forward. B=32, N=1024, F=64, PRE=64, L1=128. Output y[32].
//
// Pipeline (5 kernels, deterministic, no atomics):
//   k_deg      : disq[b,n] = rsqrt(rowsum(A))                 (pure 128 MB read)
//   k_xt       : xtb[b,f,j] = bf16(disq[b,j] * x[b,j,f])      (transposed B operand)
//   k_spmm_mlp : MFMA spmm; A staged f32 via global_load_lds (L3-warm, pre-swizzled
//                source), f32->bf16 cvt in-reg -> h in LDS -> values -> logits
//   k_tail     : softmax (redundant per chunk-block) + 128-node pool slice -> vpart
//   k_out      : y[b] = (sum_ch vpart) . Wout + bout

#define N_ 1024
#define F_ 64

typedef short s16x8 __attribute__((ext_vector_type(8)));
typedef float f32x4 __attribute__((ext_vector_type(4)));
typedef unsigned short u16x8 __attribute__((ext_vector_type(8)));

__device__ __forceinline__ unsigned short bf16rne(float f) {
  union { float f; unsigned u; } v; v.f = f;
  unsigned r = v.u + 0x7fffu + ((v.u >> 16) & 1u);
  return (unsigned short)(r >> 16);
}

__device__ __forceinline__ void fma_row(float (&a)[4], const float4 av,
                                        const float4 x0, const float4 x1,
                                        const float4 x2, const float4 x3) {
  a[0] += av.x * x0.x + av.y * x1.x + av.z * x2.x + av.w * x3.x;
  a[1] += av.x * x0.y + av.y * x1.y + av.z * x2.y + av.w * x3.y;
  a[2] += av.x * x0.z + av.y * x1.z + av.z * x2.z + av.w * x3.z;
  a[3] += av.x * x0.w + av.y * x1.w + av.z * x2.w + av.w * x3.w;
}

// global -> LDS direct DMA, 16B per lane; LDS dest = wave-uniform base + lane*16
__device__ __forceinline__ void stage16(const void* g, void* l) {
  auto gp = reinterpret_cast<const __attribute__((address_space(1))) void*>(
      reinterpret_cast<uintptr_t>(g));
  auto lp = reinterpret_cast<__attribute__((address_space(3))) void*>(
      reinterpret_cast<uintptr_t>(l));
  __builtin_amdgcn_global_load_lds(gp, lp, 16, 0, 0);
}

// ---------------- degree + d^-1/2 (pure read; warms L3 for spmm) ----------------
__global__ __launch_bounds__(256) void k_deg(const float* __restrict__ A,
                                             float* __restrict__ disq) {
  const int row  = blockIdx.x * 4 + (threadIdx.x >> 6);   // [0, B*N)
  const int lane = threadIdx.x & 63;
  const float4* a4 = (const float4*)(A + (size_t)row * N_);
  float s = 0.f;
#pragma unroll
  for (int it = 0; it < 4; ++it) {
    float4 v = a4[it * 64 + lane];
    s += v.x + v.y + v.z + v.w;
  }
#pragma unroll
  for (int off = 32; off > 0; off >>= 1) s += __shfl_down(s, off, 64);
  if (lane == 0) {
    float d = (s != 0.f) ? s : 1.f;
    disq[row] = rsqrtf(d);
  }
}

// ---------------- xtb[b][f][j] = bf16(d_j * x[b][j][f]) ----------------
__global__ __launch_bounds__(256) void k_xt(const float* __restrict__ x,
                                            const float* __restrict__ disq,
                                            unsigned short* __restrict__ xtb) {
  __shared__ float xs[64][68];
  const int b = blockIdx.y, j0 = blockIdx.x * 64, t = threadIdx.x;
  const float* xb = x + ((size_t)b << 16);
  const float* dq = disq + (b << 10);
#pragma unroll
  for (int it = 0; it < 4; ++it) {
    int idx = it * 1024 + t * 4;
    int jj = idx >> 6, ff = idx & 63;
    float4 vv = *(const float4*)&xb[(size_t)(j0 + jj) * F_ + ff];
    float sc = dq[j0 + jj];
    vv.x *= sc; vv.y *= sc; vv.z *= sc; vv.w *= sc;
    *(float4*)&xs[jj][ff] = vv;
  }
  __syncthreads();
  const int f = t & 63, ch = t >> 6;
  u16x8 o0, o1;
#pragma unroll
  for (int jj = 0; jj < 8; ++jj) o0[jj] = bf16rne(xs[ch * 16 + jj][f]);
#pragma unroll
  for (int jj = 0; jj < 8; ++jj) o1[jj] = bf16rne(xs[ch * 16 + 8 + jj][f]);
  unsigned short* dst = xtb + (size_t)(b * 64 + f) * N_ + j0 + ch * 16;
  *(u16x8*)dst = o0;
  *(u16x8*)(dst + 8) = o1;
}

// ------- fused: DMA-staged MFMA spmm (A f32 direct) -> h -> values -> logits -------
// 4 waves. Staging roles: waves 0/1 -> A rows 0-31/32-63 (f32, 256B rows,
// 16x16B slots, slot^=row&15); waves 2/3 -> B rows 0-31/32-63 (bf16, 128B rows,
// 8x16B slots, slot^=row&7). Pre-swizzled global source, linear LDS dest.
// Buffers: buf k at smem + k*24576: A [0,16384), B [16384,24576).
__global__ __launch_bounds__(256, 3) void k_spmm_mlp(const float* __restrict__ Af,
                                                     const unsigned short* __restrict__ xtb,
                                                     const float* __restrict__ x,
                                                     const float* __restrict__ disq,
                                                     const float* __restrict__ alphap,
                                                     const float* __restrict__ Wpre,
                                                     const float* __restrict__ bpre,
                                                     const float* __restrict__ Wfc1,
                                                     const float* __restrict__ bfc1,
                                                     const float* __restrict__ Wkeys,
                                                     const float* __restrict__ bkeysp,
                                                     float* __restrict__ values,
                                                     float* __restrict__ logits) {
  // Staging: [0,49152) = 2 x 24576. MLP aliases: hs f32[64][68] @0,
  // wft f32[64][128] @17408, part f32[64][16] @50176. Total 54272 -> 3 blocks/CU.
  __shared__ __attribute__((aligned(16))) char smem[54272];
  float (*hs)[68]   = (float(*)[68])(smem);
  float (*wft)[128] = (float(*)[128])(smem + 17408);
  float (*part)[16] = (float(*)[16])(smem + 50176);

  const int t  = threadIdx.x;
  const int b  = blockIdx.x;          // batch
  const int i0 = blockIdx.y * 64;     // row block
  const int w  = t >> 6, l = t & 63;
  const int lr = l & 15, kq = l >> 4;
  const size_t bb = ((size_t)b << 20);

  // ---- staging addressing ----
  const int half = (w & 1) * 32;
  // A waves (w<2): 8 instrs x (4 rows x 256B); lane covers row srow4, slot mslot.
  const int srow4 = l >> 4;           // 0..3
  const int mslot = l & 15;           // 16B slot within 256B row
  const float* gA0 = Af + bb + (size_t)(i0 + half + srow4) * 1024;
  int xoff[4];
#pragma unroll
  for (int q = 0; q < 4; ++q) xoff[q] = (mslot ^ ((q * 4 + srow4) & 15)) << 2;
  // B waves (w>=2): 4 instrs x (8 rows x 128B); lane covers row srow8, slot l&7.
  const int srow8 = l >> 3;           // 0..7
  const int schB  = ((l & 7) ^ srow8) * 8;   // pre-swizzled source chunk (shorts)
  const unsigned short* gsB = xtb + (size_t)(b * 64 + half + srow8) * N_ + schB;

  auto STAGE = [&](char* bufp, int ksv) {
    if (w < 2) {
      const int ko = ksv * 64;        // f32 k-offset
#pragma unroll
      for (int j = 0; j < 8; ++j)
        stage16(gA0 + (size_t)j * 4096 + xoff[j & 3] + ko,
                bufp + (half + j * 4) * 256);
    } else {
      const int ko = ksv * 64;        // bf16 k-offset
#pragma unroll
      for (int j = 0; j < 4; ++j)
        stage16(gsB + (size_t)j * 8 * N_ + ko,
                bufp + 16384 + half * 128 + j * 1024);
    }
  };

  // ---- prologue: DMA K-step 0 into buf0 ----
  STAGE(smem, 0);
  __syncthreads();   // implicit vmcnt(0): DMA complete

  f32x4 acc0 = {0.f, 0.f, 0.f, 0.f}, acc1 = acc0, acc2 = acc0, acc3 = acc0;
  const int arow = w * 16 + lr;       // local output row; arow&15 == lr
  const int swB = (lr & 7) << 4;      // B row-XOR for fragment reads
  int cur = 0;

  for (int ks = 0; ks < 16; ++ks) {
    if (ks < 15) STAGE(smem + (cur ^ 1) * 24576, ks + 1);  // fire-and-forget DMA
    const char* cb = smem + cur * 24576;
#pragma unroll
    for (int s = 0; s < 2; ++s) {
      // A fragment: global slots m0,m0+1 -> LDS slots (m^lr); cvt f32->bf16 RNE
      const int m0 = s * 8 + kq * 2;
      f32x4 alo = *(const f32x4*)(cb + arow * 256 + ((m0 ^ lr) << 4));
      f32x4 ahi = *(const f32x4*)(cb + arow * 256 + (((m0 + 1) ^ lr) << 4));
      s16x8 af;
      af[0] = (short)bf16rne(alo[0]); af[1] = (short)bf16rne(alo[1]);
      af[2] = (short)bf16rne(alo[2]); af[3] = (short)bf16rne(alo[3]);
      af[4] = (short)bf16rne(ahi[0]); af[5] = (short)bf16rne(ahi[1]);
      af[6] = (short)bf16rne(ahi[2]); af[7] = (short)bf16rne(ahi[3]);
      const int ch = ((kq + 4 * s) << 4);   // B chunk byte within 128B row
      s16x8 b0 = *(const s16x8*)(cb + 16384 + (0 * 16 + lr) * 128 + (ch ^ swB));
      s16x8 b1 = *(const s16x8*)(cb + 16384 + (1 * 16 + lr) * 128 + (ch ^ swB));
      s16x8 b2 = *(const s16x8*)(cb + 16384 + (2 * 16 + lr) * 128 + (ch ^ swB));
      s16x8 b3 = *(const s16x8*)(cb + 16384 + (3 * 16 + lr) * 128 + (ch ^ swB));
      acc0 = __builtin_amdgcn_mfma_f32_16x16x32_bf16(af, b0, acc0, 0, 0, 0);
      acc1 = __builtin_amdgcn_mfma_f32_16x16x32_bf16(af, b1, acc1, 0, 0, 0);
      acc2 = __builtin_amdgcn_mfma_f32_16x16x32_bf16(af, b2, acc2, 0, 0, 0);
      acc3 = __builtin_amdgcn_mfma_f32_16x16x32_bf16(af, b3, acc3, 0, 0, 0);
    }
    __syncthreads();   // drains DMA after full MFMA phase of cover
    cur ^= 1;
  }

  // ---- epilogue: h tile into LDS (staging bufs now dead) ----
  const float alpha = alphap[0];
  const float* dq = disq + (b << 10);
  const float* xb = x + ((size_t)b << 16);
  const int rl = w * 16 + kq * 4;     // local row base for C/D (col=lr, row=kq*4+r)
#pragma unroll
  for (int r = 0; r < 4; ++r) {
    float di = dq[i0 + rl + r];
    size_t ro = (size_t)(i0 + rl + r) * F_;
    hs[rl + r][0  + lr] = alpha * xb[ro + 0  + lr] + di * acc0[r];
    hs[rl + r][16 + lr] = alpha * xb[ro + 16 + lr] + di * acc1[r];
    hs[rl + r][32 + lr] = alpha * xb[ro + 32 + lr] + di * acc2[r];
    hs[rl + r][48 + lr] = alpha * xb[ro + 48 + lr] + di * acc3[r];
  }
  // load Wpre transposed into wft while hs writes settle
#pragma unroll
  for (int it = 0; it < 4; ++it) {
    int idx = it * 1024 + t * 4;
    float4 wv = *(const float4*)&Wpre[idx];
    int p = idx >> 6, f = idx & 63;
    wft[f + 0][p] = wv.x; wft[f + 1][p] = wv.y; wft[f + 2][p] = wv.z; wft[f + 3][p] = wv.w;
  }
  __syncthreads();

  // ---- phase 1: values tile ----
  const size_t base = ((size_t)(b * 16 + blockIdx.y)) * 4096;
  const int cg = t & 15, rg = t >> 4;
  float acc[4][4] = {{0.f}};
#pragma unroll
  for (int q = 0; q < 16; ++q) {
    float4 xv0 = *(float4*)&wft[q * 4 + 0][cg * 4];
    float4 xv1 = *(float4*)&wft[q * 4 + 1][cg * 4];
    float4 xv2 = *(float4*)&wft[q * 4 + 2][cg * 4];
    float4 xv3 = *(float4*)&wft[q * 4 + 3][cg * 4];
#pragma unroll
    for (int k = 0; k < 4; ++k) {
      float4 av = *(float4*)&hs[rg * 4 + k][q * 4];
      fma_row(acc[k], av, xv0, xv1, xv2, xv3);
    }
  }
  float4 bp = *(const float4*)&bpre[cg * 4];
  __syncthreads();   // phase-1 reads of hs/wft complete before overwrite
#pragma unroll
  for (int k = 0; k < 4; ++k) {
    float4 o;
    o.x = fmaxf(acc[k][0] + bp.x, 0.f);
    o.y = fmaxf(acc[k][1] + bp.y, 0.f);
    o.z = fmaxf(acc[k][2] + bp.z, 0.f);
    o.w = fmaxf(acc[k][3] + bp.w, 0.f);
    *(float4*)&hs[rg * 4 + k][cg * 4] = o;
    *(float4*)&values[base + (size_t)(rg * 4 + k) * 64 + cg * 4] = o;
  }
#pragma unroll
  for (int it = 0; it < 8; ++it) {
    int idx = it * 1024 + t * 4;
    int ll = idx >> 6, p = idx & 63;
    float4 wv = *(const float4*)&Wfc1[idx];
    wft[p + 0][ll] = wv.x; wft[p + 1][ll] = wv.y; wft[p + 2][ll] = wv.z; wft[p + 3][ll] = wv.w;
  }
  __syncthreads();

  // ---- phase 2: logits ----
  const int lg = cg;
  float acc_a[4][4] = {{0.f}};
  float acc_b[4][4] = {{0.f}};
#pragma unroll
  for (int q = 0; q < 16; ++q) {
    float4 w0a = *(float4*)&wft[q * 4 + 0][lg * 8];
    float4 w0b = *(float4*)&wft[q * 4 + 0][lg * 8 + 4];
    float4 w1a = *(float4*)&wft[q * 4 + 1][lg * 8];
    float4 w1b = *(float4*)&wft[q * 4 + 1][lg * 8 + 4];
    float4 w2a = *(float4*)&wft[q * 4 + 2][lg * 8];
    float4 w2b = *(float4*)&wft[q * 4 + 2][lg * 8 + 4];
    float4 w3a = *(float4*)&wft[q * 4 + 3][lg * 8];
    float4 w3b = *(float4*)&wft[q * 4 + 3][lg * 8 + 4];
#pragma unroll
    for (int k = 0; k < 4; ++k) {
      float4 vv = *(float4*)&hs[rg * 4 + k][q * 4];
      fma_row(acc_a[k], vv, w0a, w1a, w2a, w3a);
      fma_row(acc_b[k], vv, w0b, w1b, w2b, w3b);
    }
  }
  float4 bfa = *(const float4*)&bfc1[lg * 8];
  float4 bfb = *(const float4*)&bfc1[lg * 8 + 4];
  float4 wka = *(const float4*)&Wkeys[lg * 8];
  float4 wkb = *(const float4*)&Wkeys[lg * 8 + 4];
#pragma unroll
  for (int k = 0; k < 4; ++k) {
    float lp = 0.f;
    lp += fmaxf(acc_a[k][0] + bfa.x, 0.f) * wka.x;
    lp += fmaxf(acc_a[k][1] + bfa.y, 0.f) * wka.y;
    lp += fmaxf(acc_a[k][2] + bfa.z, 0.f) * wka.z;
    lp += fmaxf(acc_a[k][3] + bfa.w, 0.f) * wka.w;
    lp += fmaxf(acc_b[k][0] + bfb.x, 0.f) * wkb.x;
    lp += fmaxf(acc_b[k][1] + bfb.y, 0.f) * wkb.y;
    lp += fmaxf(acc_b[k][2] + bfb.z, 0.f) * wkb.z;
    lp += fmaxf(acc_b[k][3] + bfb.w, 0.f) * wkb.w;
    part[rg * 4 + k][lg] = lp;
  }
  __syncthreads();
  if (t < 64) {
    float s = bkeysp[0];
#pragma unroll
    for (int g = 0; g < 16; ++g) s += part[t][g];
    logits[(b * 16 + blockIdx.y) * 64 + t] = s;
  }
}

// ------- tail: redundant softmax per chunk-block + 128-node pool slice -------
__global__ __launch_bounds__(1024) void k_tail(const float* __restrict__ logits,
                                               const float* __restrict__ values,
                                               float* __restrict__ vpart) {
  const int c = blockIdx.x, b = blockIdx.y, t = threadIdx.x;
  __shared__ float sc[1024];
  __shared__ float red[16];
  __shared__ float pool[16][64];
  const float isq2 = 0.70710678118654752f;
  float lv = logits[(b << 10) + t] * isq2;
  float m = lv;
#pragma unroll
  for (int off = 32; off > 0; off >>= 1) m = fmaxf(m, __shfl_xor(m, off, 64));
  if ((t & 63) == 0) red[t >> 6] = m;
  __syncthreads();
  m = red[0];
#pragma unroll
  for (int i = 1; i < 16; ++i) m = fmaxf(m, red[i]);
  float e = expf(lv - m);
  float s = e;
#pragma unroll
  for (int off = 32; off > 0; off >>= 1) s += __shfl_xor(s, off, 64);
  __syncthreads();
  if ((t & 63) == 0) red[t >> 6] = s;
  __syncthreads();
  s = red[0];
#pragma unroll
  for (int i = 1; i < 16; ++i) s += red[i];
  sc[t] = e * (1.f / s);
  __syncthreads();
  const int col = t & 63, g = t >> 6;
  const float* vb = values + ((size_t)b << 16);
  float acc = 0.f;
#pragma unroll
  for (int k = 0; k < 8; ++k) {
    int n = c * 128 + g + 16 * k;
    acc += sc[n] * vb[(size_t)n * 64 + col];
  }
  pool[g][col] = acc;
  __syncthreads();
  if (t < 64) {
    float v = 0.f;
#pragma unroll
    for (int gg = 0; gg < 16; ++gg) v += pool[gg][t];
    vpart[(b * 8 + c) * 64 + t] = v;
  }
}

// ---------------- final y ----------------
__global__ __launch_bounds__(256) void k_out(const float* __restrict__ vpart,
                                             const float* __restrict__ Wout,
                                             const float* __restrict__ boutp,
                                             float* __restrict__ y) {
  const int t = threadIdx.x, w = t >> 6, lane = t & 63;
#pragma unroll
  for (int it = 0; it < 8; ++it) {
    int b = w * 8 + it;
    float v = 0.f;
#pragma unroll
    for (int ch = 0; ch < 8; ++ch) v += vpart[(b * 8 + ch) * 64 + lane];
    float p = v * Wout[lane];
#pragma unroll
    for (int off = 32; off > 0; off >>= 1) p += __shfl_down(p, off, 64);
    if (lane == 0) y[b] = p + boutp[0];
  }
}

extern "C" void kernel_launch(void* const* d_in, const int* in_sizes, int n_in,
                              void* d_out, int out_size, void* d_ws, size_t ws_size,
                              hipStream_t stream) {
  const float* x     = (const float*)d_in[0];
  const float* A     = (const float*)d_in[1];
  const float* alpha = (const float*)d_in[2];
  const float* Wpre  = (const float*)d_in[3];
  const float* bpre  = (const float*)d_in[4];
  const float* Wfc1  = (const float*)d_in[5];
  const float* bfc1  = (const float*)d_in[6];
  const float* Wkeys = (const float*)d_in[7];
  const float* bkeys = (const float*)d_in[8];
  const float* Wout  = (const float*)d_in[9];
  const float* bout  = (const float*)d_in[10];
  float* y = (float*)d_out;

  float* ws     = (float*)d_ws;
  float* disq   = ws;                   // 32768 f32
  float* values = disq + 32768;         // 2097152 f32
  float* logits = values + 2097152;     // 32768 f32
  float* vpart  = logits + 32768;       // 16384 f32
  unsigned short* xtb = (unsigned short*)(vpart + 16384);   // 2097152 bf16

  k_deg     <<<dim3(8192),   dim3(256),  0, stream>>>(A, disq);
  k_xt      <<<dim3(16, 32), dim3(256),  0, stream>>>(x, disq, xtb);
  k_spmm_mlp<<<dim3(32, 16), dim3(256),  0, stream>>>(A, xtb, x, disq, alpha,
                                                      Wpre, bpre, Wfc1, bfc1, Wkeys, bkeys,
                                                      values, logits);
  k_tail    <<<dim3(8, 32),  dim3(1024), 0, stream>>>(logits, values, vpart);
  k_out     <<<dim3(1),      dim3(256),  0, stream>>>(vpart, Wout, bout, y);
}